// Round 14
// baseline (647.809 us; speedup 1.0000x reference)
//
#include <hip/hip_runtime.h>

#define T_TOK 8192
#define DIMSZ 512
#define HIDSZ 1536
#define SHIDSZ 3072
#define NE 8

typedef __attribute__((ext_vector_type(4))) float f32x4;
typedef __attribute__((ext_vector_type(8))) short s16x8;

__device__ __forceinline__ unsigned short f2bf(float f) {
  unsigned int u = __float_as_uint(f);
  u += 0x7fff + ((u >> 16) & 1);
  return (unsigned short)(u >> 16);
}

__device__ __forceinline__ void async16(void* lds, const void* g) {
  __builtin_amdgcn_global_load_lds((const __attribute__((address_space(1))) void*)g,
                                   (__attribute__((address_space(3))) void*)lds,
                                   16, 0, 0);
}

// ---------------- convert fp32 -> bf16 (vectorized) ----------------
__global__ void cvt_bf16(const float* __restrict__ s, unsigned short* __restrict__ d, int n4) {
  int i = blockIdx.x * blockDim.x + threadIdx.x;
  if (i < n4) {
    float4 v = ((const float4*)s)[i];
    ushort4 o;
    o.x = f2bf(v.x); o.y = f2bf(v.y); o.z = f2bf(v.z); o.w = f2bf(v.w);
    ((ushort4*)d)[i] = o;
  }
}

// ---------------- gate: logits, softmax, top-2, block-aggregated counts ------
#define GATE_BLOCKS 256
#define GATE_TPB (T_TOK / GATE_BLOCKS)
#define GATE_TPW (GATE_TPB / 4)

__global__ __launch_bounds__(256) void gate_kernel(
    const float* __restrict__ x, const float* __restrict__ gw,
    float* __restrict__ tw, int* __restrict__ ti, int* __restrict__ cnt) {
  __shared__ int lcnt[NE];
  const int tid = threadIdx.x;
  if (tid < NE) lcnt[tid] = 0;
  __syncthreads();
  const int w = tid >> 6, l = tid & 63;

  float gv[NE][8];
  const float* gbase = gw + l * 8;
#pragma unroll
  for (int e = 0; e < NE; ++e)
#pragma unroll
    for (int j = 0; j < 8; ++j) gv[e][j] = gbase[e * DIMSZ + j];

  const int tok0 = blockIdx.x * GATE_TPB + w * GATE_TPW;
  for (int it = 0; it < GATE_TPW; ++it) {
    const int t = tok0 + it;
    const float* xr = x + (size_t)t * DIMSZ + l * 8;
    float xv[8];
#pragma unroll
    for (int j = 0; j < 8; ++j) xv[j] = xr[j];
    float p[NE];
#pragma unroll
    for (int e = 0; e < NE; ++e) {
      float s = 0.f;
#pragma unroll
      for (int j = 0; j < 8; ++j) s = fmaf(xv[j], gv[e][j], s);
      p[e] = s;
    }
#pragma unroll
    for (int e = 0; e < NE; ++e) {
      float v = p[e];
#pragma unroll
      for (int off = 32; off > 0; off >>= 1) v += __shfl_xor(v, off);
      p[e] = v;
    }
    float m = p[0];
#pragma unroll
    for (int e = 1; e < NE; ++e) m = fmaxf(m, p[e]);
    float ex[NE], s = 0.f;
#pragma unroll
    for (int e = 0; e < NE; ++e) { ex[e] = __expf(p[e] - m); s += ex[e]; }
    float inv = 1.f / s;
    int e0 = 0; float v0 = p[0];
#pragma unroll
    for (int e = 1; e < NE; ++e) if (p[e] > v0) { v0 = p[e]; e0 = e; }
    int e1 = -1; float v1 = -3.4e38f;
#pragma unroll
    for (int e = 0; e < NE; ++e) if (e != e0 && p[e] > v1) { v1 = p[e]; e1 = e; }
    if (l == 0) {
      ti[2 * t] = e0;     tw[2 * t] = ex[e0] * inv;
      ti[2 * t + 1] = e1; tw[2 * t + 1] = ex[e1] * inv;
      atomicAdd(&lcnt[e0], 1);
      atomicAdd(&lcnt[e1], 1);
    }
  }
  __syncthreads();
  if (tid < NE) atomicAdd(&cnt[tid], lcnt[tid]);
}

// ---------------- exclusive scan over 8 expert counts ----------------
__global__ void scan_kernel(const int* __restrict__ cnt, int* __restrict__ base,
                            int* __restrict__ cursor) {
  if (threadIdx.x == 0 && blockIdx.x == 0) {
    int r = 0;
    for (int e = 0; e < NE; ++e) { base[e] = r; cursor[e] = r; r += cnt[e]; }
  }
}

// ---------------- scatter (block-aggregated) ----------------
__global__ __launch_bounds__(256) void scatter_kernel(
    const int* __restrict__ ti, int* __restrict__ cursor,
    int* __restrict__ tok, int* __restrict__ dst) {
  __shared__ int lcnt[NE], gbase[NE];
  const int tid = threadIdx.x;
  if (tid < NE) lcnt[tid] = 0;
  __syncthreads();
  const int t = blockIdx.x * 256 + tid;
  const int e0 = ti[2 * t], e1 = ti[2 * t + 1];
  const int p0 = atomicAdd(&lcnt[e0], 1);
  const int p1 = atomicAdd(&lcnt[e1], 1);
  __syncthreads();
  if (tid < NE) gbase[tid] = atomicAdd(&cursor[tid], lcnt[tid]);
  __syncthreads();
  const int i0 = gbase[e0] + p0, i1 = gbase[e1] + p1;
  tok[i0] = t; dst[i0] = 2 * t;
  tok[i1] = t; dst[i1] = 2 * t + 1;
}

// =====================================================================
// GEMM1 (merged routed+shared): g = silu(A@W1^T) * (A@W3^T), bf16 out.
// R4-proven core: tile 128M x 64N, BK=64 (swz chunk^(row&7), 0 conflicts),
// single-buffered 32KB LDS, (256,3). XCD swizzle: x-dim 576 = 8*72,
// bx = (x%8)*72 + x/8 gives each XCD a contiguous (e,mt) slice so weight
// panels stay L2-resident (xcd = physical x % 8 since 576 % 8 == 0).
// =====================================================================
__global__ __launch_bounds__(256, 3) void gemm1_all(
    const unsigned short* __restrict__ xb, const int* __restrict__ tok,
    const unsigned short* __restrict__ w1b, const unsigned short* __restrict__ w3b,
    const unsigned short* __restrict__ sw1b, const unsigned short* __restrict__ sw3b,
    unsigned short* __restrict__ g_rt, unsigned short* __restrict__ g_sh,
    const int* __restrict__ cnt, const int* __restrict__ base) {
  const int bx = (blockIdx.x & 7) * 72 + (blockIdx.x >> 3);  // bijective, 576=8*72
  const int e = bx >> 6, mt = bx & 63;
  const int n0 = blockIdx.y * 64;
  int cntE, rowbase, N;
  const unsigned short *B1, *B3;
  unsigned short* G;
  bool indirect;
  if (e < NE) {
    N = HIDSZ;
    if (n0 >= HIDSZ) return;
    cntE = cnt[e];
    if (mt * 128 >= cntE) return;
    rowbase = base[e];
    B1 = w1b + (size_t)e * HIDSZ * DIMSZ + (size_t)n0 * DIMSZ;
    B3 = w3b + (size_t)e * HIDSZ * DIMSZ + (size_t)n0 * DIMSZ;
    G = g_rt + (size_t)rowbase * HIDSZ;
    indirect = true;
  } else {
    N = SHIDSZ; cntE = T_TOK; rowbase = 0;
    B1 = sw1b + (size_t)n0 * DIMSZ;
    B3 = sw3b + (size_t)n0 * DIMSZ;
    G = g_sh;
    indirect = false;
  }
  const int m0 = mt * 128;

  __shared__ __align__(16) unsigned short As[128 * 64];
  __shared__ __align__(16) unsigned short B1s[64 * 64];
  __shared__ __align__(16) unsigned short B3s[64 * 64];

  const int tid = threadIdx.x;
  const int w = tid >> 6, lane = tid & 63;
  const int wr = w >> 1, wc = w & 1;
  const int lhi = lane >> 4, llo = lane & 15;

  const unsigned short* aSrc[4];
  int aDst[4];
#pragma unroll
  for (int i = 0; i < 4; ++i) {
    int L = i * 256 + tid, row = L >> 3, c = L & 7, sc = c ^ (row & 7);
    int ar = min(m0 + row, cntE - 1);
    int rowg = indirect ? tok[rowbase + ar] : ar;
    aSrc[i] = xb + (size_t)rowg * DIMSZ + sc * 8;
    aDst[i] = (i * 256 + (tid & ~63)) * 8;
  }
  const unsigned short *b1Src[2], *b3Src[2];
  int bDst[2];
#pragma unroll
  for (int i = 0; i < 2; ++i) {
    int L = i * 256 + tid, row = L >> 3, c = L & 7, sc = c ^ (row & 7);
    b1Src[i] = B1 + (size_t)row * DIMSZ + sc * 8;
    b3Src[i] = B3 + (size_t)row * DIMSZ + sc * 8;
    bDst[i] = (i * 256 + (tid & ~63)) * 8;
  }

  int aOff[4][2], bOff[2][2];
#pragma unroll
  for (int m = 0; m < 4; ++m) {
    int r = wr * 64 + m * 16 + llo;
#pragma unroll
    for (int s = 0; s < 2; ++s)
      aOff[m][s] = r * 64 + (((lhi + 4 * s) ^ (r & 7)) * 8);
  }
#pragma unroll
  for (int n = 0; n < 2; ++n) {
    int r = wc * 32 + n * 16 + llo;
#pragma unroll
    for (int s = 0; s < 2; ++s)
      bOff[n][s] = r * 64 + (((lhi + 4 * s) ^ (r & 7)) * 8);
  }

  f32x4 acc1[4][2], acc3[4][2];
#pragma unroll
  for (int m = 0; m < 4; ++m)
#pragma unroll
    for (int n = 0; n < 2; ++n) {
      acc1[m][n] = f32x4{0.f, 0.f, 0.f, 0.f};
      acc3[m][n] = f32x4{0.f, 0.f, 0.f, 0.f};
    }

  for (int k0 = 0; k0 < DIMSZ; k0 += 64) {
#pragma unroll
    for (int i = 0; i < 4; ++i) async16(&As[aDst[i]], aSrc[i] + k0);
#pragma unroll
    for (int i = 0; i < 2; ++i) {
      async16(&B1s[bDst[i]], b1Src[i] + k0);
      async16(&B3s[bDst[i]], b3Src[i] + k0);
    }
    __syncthreads();
#pragma unroll
    for (int s = 0; s < 2; ++s) {
      s16x8 a[4], b1f[2], b3f[2];
#pragma unroll
      for (int m = 0; m < 4; ++m) a[m] = *(const s16x8*)&As[aOff[m][s]];
#pragma unroll
      for (int n = 0; n < 2; ++n) {
        b1f[n] = *(const s16x8*)&B1s[bOff[n][s]];
        b3f[n] = *(const s16x8*)&B3s[bOff[n][s]];
      }
#pragma unroll
      for (int m = 0; m < 4; ++m)
#pragma unroll
        for (int n = 0; n < 2; ++n) {
          acc1[m][n] = __builtin_amdgcn_mfma_f32_16x16x32_bf16(a[m], b1f[n], acc1[m][n], 0, 0, 0);
          acc3[m][n] = __builtin_amdgcn_mfma_f32_16x16x32_bf16(a[m], b3f[n], acc3[m][n], 0, 0, 0);
        }
    }
    __syncthreads();
  }

#pragma unroll
  for (int m = 0; m < 4; ++m)
#pragma unroll
    for (int n = 0; n < 2; ++n)
#pragma unroll
      for (int q = 0; q < 4; ++q) {
        int r = wr * 64 + m * 16 + lhi * 4 + q;
        if (m0 + r < cntE) {
          float h1 = acc1[m][n][q], h3 = acc3[m][n][q];
          float val = (h1 / (1.f + __expf(-h1))) * h3;
          G[(size_t)(m0 + r) * N + n0 + wc * 32 + n * 16 + llo] = f2bf(val);
        }
      }
}

// =====================================================================
// GEMM2 cores (R5-proven: 64M x 128N, BK=64, dbuf 48KB, counted vmcnt(6)).
// Split: gemm2_shared runs FIRST, plain stores covering every out element
// (replaces the memset); gemm2_routed runs second (same stream => ordered)
// and atomicAdds the weighted routed contributions.
// =====================================================================
template <bool ROUTED>
__device__ __forceinline__ void gemm2_core(
    const unsigned short* __restrict__ A, const unsigned short* __restrict__ B,
    int K, int cntE, int m0, int n0, int rowbase,
    const int* __restrict__ dst, const float* __restrict__ tw,
    float* __restrict__ out) {
  __shared__ __align__(16) unsigned short As[2 * 64 * 64];
  __shared__ __align__(16) unsigned short Bs[2 * 128 * 64];

  const int tid = threadIdx.x;
  const int w = tid >> 6, lane = tid & 63;
  const int wr = w >> 1, wc = w & 1;
  const int lhi = lane >> 4, llo = lane & 15;

  const unsigned short* aSrc[2];
  int aDst[2];
#pragma unroll
  for (int i = 0; i < 2; ++i) {
    int L = i * 256 + tid, row = L >> 3, c = L & 7, sc = c ^ (row & 7);
    int ar = min(m0 + row, cntE - 1);
    aSrc[i] = A + (size_t)ar * K + sc * 8;
    aDst[i] = (i * 256 + (tid & ~63)) * 8;
  }
  const unsigned short* bSrc[4];
  int bDst[4];
#pragma unroll
  for (int i = 0; i < 4; ++i) {
    int L = i * 256 + tid, row = L >> 3, c = L & 7, sc = c ^ (row & 7);
    bSrc[i] = B + (size_t)row * K + sc * 8;
    bDst[i] = (i * 256 + (tid & ~63)) * 8;
  }

  int aOff[2][2], bOff[4][2];
#pragma unroll
  for (int m = 0; m < 2; ++m) {
    int r = wr * 32 + m * 16 + llo;
#pragma unroll
    for (int s = 0; s < 2; ++s)
      aOff[m][s] = r * 64 + (((lhi + 4 * s) ^ (r & 7)) * 8);
  }
#pragma unroll
  for (int n = 0; n < 4; ++n) {
    int r = wc * 64 + n * 16 + llo;
#pragma unroll
    for (int s = 0; s < 2; ++s)
      bOff[n][s] = r * 64 + (((lhi + 4 * s) ^ (r & 7)) * 8);
  }

  f32x4 acc[2][4];
#pragma unroll
  for (int i = 0; i < 2; ++i)
#pragma unroll
    for (int j = 0; j < 4; ++j) acc[i][j] = f32x4{0.f, 0.f, 0.f, 0.f};

  const int nt = K >> 6;
  int cur = 0;
#pragma unroll
  for (int i = 0; i < 2; ++i) async16(&As[aDst[i]], aSrc[i]);
#pragma unroll
  for (int i = 0; i < 4; ++i) async16(&Bs[bDst[i]], bSrc[i]);

  for (int t = 0; t < nt; ++t) {
    const bool more = (t + 1) < nt;
    if (more) {
      const int k1 = (t + 1) << 6;
      const int nxtA = (cur ^ 1) * 4096, nxtB = (cur ^ 1) * 8192;
#pragma unroll
      for (int i = 0; i < 2; ++i) async16(&As[nxtA + aDst[i]], aSrc[i] + k1);
#pragma unroll
      for (int i = 0; i < 4; ++i) async16(&Bs[nxtB + bDst[i]], bSrc[i] + k1);
      asm volatile("s_waitcnt vmcnt(6)" ::: "memory");
    } else {
      asm volatile("s_waitcnt vmcnt(0)" ::: "memory");
    }
    __builtin_amdgcn_s_barrier();
    const int cA = cur * 4096, cB = cur * 8192;
#pragma unroll
    for (int s = 0; s < 2; ++s) {
      s16x8 a[2], b[4];
#pragma unroll
      for (int m = 0; m < 2; ++m) a[m] = *(const s16x8*)&As[cA + aOff[m][s]];
#pragma unroll
      for (int n = 0; n < 4; ++n) b[n] = *(const s16x8*)&Bs[cB + bOff[n][s]];
#pragma unroll
      for (int i = 0; i < 2; ++i)
#pragma unroll
        for (int j = 0; j < 4; ++j)
          acc[i][j] = __builtin_amdgcn_mfma_f32_16x16x32_bf16(a[i], b[j], acc[i][j], 0, 0, 0);
    }
    if (more) { __builtin_amdgcn_s_barrier(); cur ^= 1; }
  }

#pragma unroll
  for (int i = 0; i < 2; ++i)
#pragma unroll
    for (int q = 0; q < 4; ++q) {
      int r = wr * 32 + i * 16 + lhi * 4 + q;
      if (m0 + r < cntE) {
        if constexpr (ROUTED) {
          int d = dst[rowbase + m0 + r];
          int orow = d >> 1;
          float wgt = tw[d];
          float* orow_p = out + (size_t)orow * DIMSZ + n0 + wc * 64 + llo;
#pragma unroll
          for (int j = 0; j < 4; ++j)
            atomicAdd(&orow_p[j * 16], wgt * acc[i][j][q]);
        } else {
          int orow = m0 + r;
          float* orow_p = out + (size_t)orow * DIMSZ + n0 + wc * 64 + llo;
#pragma unroll
          for (int j = 0; j < 4; ++j)
            orow_p[j * 16] = acc[i][j][q];
        }
      }
    }
}

// shared expert: 128 x-tiles (8*16) x 4 y; plain stores (runs before routed)
__global__ __launch_bounds__(256, 3) void gemm2_shared(
    const unsigned short* __restrict__ g_sh, const unsigned short* __restrict__ sw2b,
    float* __restrict__ out) {
  const int mt = (blockIdx.x & 7) * 16 + (blockIdx.x >> 3);  // bijective, 128=8*16
  const int n0 = blockIdx.y * 128;
  gemm2_core<false>(g_sh, sw2b + (size_t)n0 * SHIDSZ, SHIDSZ, T_TOK,
                    mt * 64, n0, 0, nullptr, nullptr, out);
}

// routed: 1024 x-tiles (8*128) x 4 y; atomicAdd on top of shared result
__global__ __launch_bounds__(256, 3) void gemm2_routed(
    const unsigned short* __restrict__ g_rt, const unsigned short* __restrict__ w2b,
    const int* __restrict__ cnt, const int* __restrict__ base,
    const int* __restrict__ dst, const float* __restrict__ tw,
    float* __restrict__ out) {
  const int bx = (blockIdx.x & 7) * 128 + (blockIdx.x >> 3);  // bijective, 1024=8*128
  const int e = bx >> 7, mt = bx & 127;
  const int cntE = cnt[e];
  if (mt * 64 >= cntE) return;
  const int rowbase = base[e];
  const int n0 = blockIdx.y * 128;
  gemm2_core<true>(g_rt + (size_t)rowbase * HIDSZ,
                   w2b + (size_t)e * DIMSZ * HIDSZ + (size_t)n0 * HIDSZ,
                   HIDSZ, cntE, mt * 64, n0, rowbase, dst, tw, out);
}

extern "C" void kernel_launch(void* const* d_in, const int* in_sizes, int n_in,
                              void* d_out, int out_size, void* d_ws, size_t ws_size,
                              hipStream_t stream) {
  const float* x   = (const float*)d_in[0];
  const float* gw  = (const float*)d_in[1];
  const float* w1  = (const float*)d_in[2];
  const float* w3  = (const float*)d_in[3];
  const float* w2  = (const float*)d_in[4];
  const float* sw1 = (const float*)d_in[5];
  const float* sw3 = (const float*)d_in[6];
  const float* sw2 = (const float*)d_in[7];
  float* out = (float*)d_out;

  char* p = (char*)d_ws;
  auto alloc = [&](size_t bytes) {
    char* r = p;
    p += (bytes + 255) & ~(size_t)255;
    return r;
  };
  unsigned short* xb   = (unsigned short*)alloc((size_t)T_TOK * DIMSZ * 2);
  unsigned short* w1b  = (unsigned short*)alloc((size_t)NE * HIDSZ * DIMSZ * 2);
  unsigned short* w3b  = (unsigned short*)alloc((size_t)NE * HIDSZ * DIMSZ * 2);
  unsigned short* w2b  = (unsigned short*)alloc((size_t)NE * DIMSZ * HIDSZ * 2);
  unsigned short* sw1b = (unsigned short*)alloc((size_t)SHIDSZ * DIMSZ * 2);
  unsigned short* sw3b = (unsigned short*)alloc((size_t)SHIDSZ * DIMSZ * 2);
  unsigned short* sw2b = (unsigned short*)alloc((size_t)DIMSZ * SHIDSZ * 2);
  unsigned short* g_rt = (unsigned short*)alloc((size_t)2 * T_TOK * HIDSZ * 2);
  unsigned short* g_sh = (unsigned short*)alloc((size_t)T_TOK * SHIDSZ * 2);
  float* tw = (float*)alloc((size_t)2 * T_TOK * 4);
  int* ti   = (int*)alloc((size_t)2 * T_TOK * 4);
  int* tok  = (int*)alloc((size_t)2 * T_TOK * 4);
  int* dst  = (int*)alloc((size_t)2 * T_TOK * 4);
  int* meta = (int*)alloc(256);
  int* cnt = meta, *cursor = meta + 8, *base = meta + 16;

  auto cvt = [&](const float* s, unsigned short* d, size_t n) {
    int n4 = (int)(n / 4);
    cvt_bf16<<<(n4 + 255) / 256, 256, 0, stream>>>(s, d, n4);
  };
  cvt(x, xb, (size_t)T_TOK * DIMSZ);
  cvt(w1, w1b, (size_t)NE * HIDSZ * DIMSZ);
  cvt(w3, w3b, (size_t)NE * HIDSZ * DIMSZ);
  cvt(w2, w2b, (size_t)NE * DIMSZ * HIDSZ);
  cvt(sw1, sw1b, (size_t)SHIDSZ * DIMSZ);
  cvt(sw3, sw3b, (size_t)SHIDSZ * DIMSZ);
  cvt(sw2, sw2b, (size_t)DIMSZ * SHIDSZ);

  hipMemsetAsync(meta, 0, 64, stream);
  gate_kernel<<<GATE_BLOCKS, 256, 0, stream>>>(x, gw, tw, ti, cnt);
  scan_kernel<<<1, 64, 0, stream>>>(cnt, base, cursor);
  scatter_kernel<<<T_TOK / 256, 256, 0, stream>>>(ti, cursor, tok, dst);

  // GEMM1: routed (x-slices 0..511) + shared (512..575), XCD-swizzled
  gemm1_all<<<dim3((NE + 1) * (T_TOK / 128), SHIDSZ / 64), 256, 0, stream>>>(
      xb, tok, w1b, w3b, sw1b, sw3b, g_rt, g_sh, cnt, base);

  // GEMM2: shared first (plain stores init out), then routed (atomicAdd)
  gemm2_shared<<<dim3(T_TOK / 64, DIMSZ / 128), 256, 0, stream>>>(g_sh, sw2b, out);
  gemm2_routed<<<dim3(NE * (T_TOK / 64), DIMSZ / 128), 256, 0, stream>>>(
      g_rt, w2b, cnt, base, dst, tw, out);
}